// Round 1
// baseline (1032.726 us; speedup 1.0000x reference)
//
#include <hip/hip_runtime.h>

// LSTM(H=5, in=1) over T=2048, B=8192, + ReLU + FC head.
// Round 1: one thread per batch element (128 waves). Correctness-first
// baseline with the shared-rcp activation formulation:
//   i*g = (1-ug) / ((1+ui)(1+ug)),  h = o*tanh(c) = (1-w)/((1+uo)(1+w))
// with all weights pre-scaled by -log2e (g-rows by -2log2e) so gate
// accumulators feed v_exp_f32 directly.

#define TLEN 2048
#define HID 5

__device__ __forceinline__ float fexp2(float v) { return __builtin_amdgcn_exp2f(v); }
__device__ __forceinline__ float frcp(float v)  { return __builtin_amdgcn_rcpf(v); }

__global__ __launch_bounds__(64, 1) void lstm_fused(
    const float* __restrict__ x,      // [B, T, 1]
    const float* __restrict__ W_ih,   // [20, 1]
    const float* __restrict__ W_hh,   // [20, 5]
    const float* __restrict__ b_ih,   // [20]
    const float* __restrict__ b_hh,   // [20]
    const float* __restrict__ W_fc,   // [1, 5]
    const float* __restrict__ b_fc,   // [1]
    float* __restrict__ out, int B)
{
    const int b = blockIdx.x * 64 + threadIdx.x;
    if (b >= B) return;
    constexpr float L2E = 1.4426950408889634f;

    // Load + pre-scale weights into registers (wave-uniform values).
    // Gate order (PyTorch): rows 0-4 = i, 5-9 = f, 10-14 = g, 15-19 = o.
    float wih[20], bias[20], whh[20][HID];
#pragma unroll
    for (int j = 0; j < 20; ++j) {
        const float s = (j >= 10 && j < 15) ? (-2.0f * L2E) : (-L2E);
        wih[j]  = W_ih[j] * s;
        bias[j] = (b_ih[j] + b_hh[j]) * s;
#pragma unroll
        for (int k = 0; k < HID; ++k) whh[j][k] = W_hh[j * HID + k] * s;
    }

    float h[HID], c[HID];
#pragma unroll
    for (int k = 0; k < HID; ++k) { h[k] = 0.0f; c[k] = 0.0f; }

    const float4* xp = reinterpret_cast<const float4*>(x + (size_t)b * TLEN);
    float4 xv = xp[0];
#pragma unroll 1
    for (int t4 = 0; t4 < TLEN / 4; ++t4) {
        const int nxt = (t4 + 1 < TLEN / 4) ? (t4 + 1) : t4;
        float4 xn = xp[nxt];  // prefetch next 4 inputs
        float xq[4] = {xv.x, xv.y, xv.z, xv.w};
#pragma unroll
        for (int q = 0; q < 4; ++q) {
            const float xt = xq[q];
            float z[20];
#pragma unroll
            for (int j = 0; j < 20; ++j) {
                float a = fmaf(xt, wih[j], bias[j]);
                a = fmaf(h[0], whh[j][0], a);
                a = fmaf(h[1], whh[j][1], a);
                a = fmaf(h[2], whh[j][2], a);
                a = fmaf(h[3], whh[j][3], a);
                a = fmaf(h[4], whh[j][4], a);
                z[j] = a;   // already scaled: exp2(z) = e^{-gate} (or e^{-2g})
            }
#pragma unroll
            for (int k = 0; k < HID; ++k) {
                const float ui = fexp2(z[k]);        // e^{-zi}
                const float uf = fexp2(z[5 + k]);    // e^{-zf}
                const float ug = fexp2(z[10 + k]);   // e^{-2 zg}
                const float uo = fexp2(z[15 + k]);   // e^{-zo}
                const float f  = frcp(1.0f + uf);                                // sigmoid(zf)
                const float ig = (1.0f - ug) * frcp((1.0f + ui) * (1.0f + ug));  // i*g
                c[k] = fmaf(f, c[k], ig);
                const float w = fexp2(c[k] * (-2.0f * L2E));                     // e^{-2c}
                h[k] = (1.0f - w) * frcp((1.0f + uo) * (1.0f + w));              // o*tanh(c)
            }
        }
        xv = xn;
    }

    // Epilogue: relu(h) @ W_fc.T + b_fc
    float acc = b_fc[0];
#pragma unroll
    for (int k = 0; k < HID; ++k) acc = fmaf(fmaxf(h[k], 0.0f), W_fc[k], acc);
    out[b] = acc;
}

extern "C" void kernel_launch(void* const* d_in, const int* in_sizes, int n_in,
                              void* d_out, int out_size, void* d_ws, size_t ws_size,
                              hipStream_t stream) {
    const float* x    = (const float*)d_in[0];
    const float* W_ih = (const float*)d_in[1];
    const float* W_hh = (const float*)d_in[2];
    const float* b_ih = (const float*)d_in[3];
    const float* b_hh = (const float*)d_in[4];
    const float* W_fc = (const float*)d_in[5];
    const float* b_fc = (const float*)d_in[6];
    float* out = (float*)d_out;
    const int B = out_size;  // 8192
    lstm_fused<<<(B + 63) / 64, 64, 0, stream>>>(x, W_ih, W_hh, b_ih, b_hh, W_fc, b_fc, out, B);
}

// Round 2
// 374.458 us; speedup vs baseline: 2.7579x; 2.7579x over previous
//
#include <hip/hip_runtime.h>

// LSTM(H=5, in=1), T=2048, B=8192, + ReLU + FC head.
// Round 2: 8 lanes per batch element (1024 waves = 1/SIMD, full chip).
// Lane k (k=0..4) owns hidden unit k: computes gate rows {k,5+k,10+k,15+k},
// does the full c/h update for its unit, then the group broadcasts h[0..4]
// via DPP (quad_perm + row_shr/shl:4 with bank masks) — VALU-rate cross-lane,
// avoiding the ~100cy LDS-pipe latency of shfl/ds_swizzle.
// Lanes 5-7 duplicate unit 4 (clamped) to keep exec uniform; never read.
// Activation math (weights pre-scaled by -log2e, g-rows by -2log2e):
//   sigmoid(z) = rcp(1+u), u=exp2(zscaled)
//   i*g = (1-ug)*rcp((1+ui)(1+ug));  o*tanh(c) = (1-w)*rcp((1+uo)(1+w))

#define TLEN 2048

__device__ __forceinline__ float fexp2(float v) { return __builtin_amdgcn_exp2f(v); }
__device__ __forceinline__ float frcp(float v)  { return __builtin_amdgcn_rcpf(v); }

template<int CTRL>
__device__ __forceinline__ float dppmov(float v) {
    return __int_as_float(__builtin_amdgcn_mov_dpp(__float_as_int(v), CTRL, 0xF, 0xF, true));
}
template<int CTRL, int BANK_MASK>
__device__ __forceinline__ float dppupd(float old, float v) {
    return __int_as_float(__builtin_amdgcn_update_dpp(
        __float_as_int(old), __float_as_int(v), CTRL, 0xF, BANK_MASK, false));
}

__global__ __launch_bounds__(256, 1) void lstm_fused8(
    const float* __restrict__ x,      // [B, T, 1]
    const float* __restrict__ W_ih,   // [20, 1]
    const float* __restrict__ W_hh,   // [20, 5]
    const float* __restrict__ b_ih,   // [20]
    const float* __restrict__ b_hh,   // [20]
    const float* __restrict__ W_fc,   // [1, 5]
    const float* __restrict__ b_fc,   // [1]
    float* __restrict__ out, int B)
{
    const int tid = blockIdx.x * 256 + threadIdx.x;
    if (tid >= B * 8) return;        // B*8 == grid exactly; uniform true
    const int b = tid >> 3;          // batch element
    const int lane8 = tid & 7;       // slot within 8-lane group
    const int k = lane8 < 5 ? lane8 : 4;  // owned hidden unit (clamped)

    constexpr float L2E = 1.4426950408889634f;
    const float M2L2E = -2.0f * L2E;

    // This lane's 4 gate rows: i=k, f=5+k, g=10+k, o=15+k (PyTorch order).
    float wih[4], bias[4], whh[4][5];
    {
        const int rows[4] = {k, 5 + k, 10 + k, 15 + k};
#pragma unroll
        for (int r = 0; r < 4; ++r) {
            const int j = rows[r];
            const float s = (r == 2) ? M2L2E : -L2E;   // g-row gets -2log2e
            wih[r]  = W_ih[j] * s;
            bias[r] = (b_ih[j] + b_hh[j]) * s;
#pragma unroll
            for (int m = 0; m < 5; ++m) whh[r][m] = W_hh[j * 5 + m] * s;
        }
    }

    float c = 0.0f;
    float h0v = 0.0f, h1v = 0.0f, h2v = 0.0f, h3v = 0.0f, h4v = 0.0f;

    const float4* xp = reinterpret_cast<const float4*>(x + (size_t)b * TLEN);
    float4 xv = xp[0];
#pragma unroll 1
    for (int t4 = 0; t4 < TLEN / 4; ++t4) {
        const int nxt = (t4 + 1 < TLEN / 4) ? (t4 + 1) : t4;
        float4 xn = xp[nxt];
        float xq[4] = {xv.x, xv.y, xv.z, xv.w};
#pragma unroll
        for (int q = 0; q < 4; ++q) {
            const float xt = xq[q];
            float z[4];
#pragma unroll
            for (int r = 0; r < 4; ++r) {
                // split-accumulate to shorten the dependent chain
                float a = fmaf(xt, wih[r], bias[r]);
                a = fmaf(h0v, whh[r][0], a);
                a = fmaf(h1v, whh[r][1], a);
                float bacc = h2v * whh[r][2];
                bacc = fmaf(h3v, whh[r][3], bacc);
                bacc = fmaf(h4v, whh[r][4], bacc);
                z[r] = a + bacc;
            }
            const float ui = fexp2(z[0]);   // e^{-zi}
            const float uf = fexp2(z[1]);   // e^{-zf}
            const float ug = fexp2(z[2]);   // e^{-2 zg}
            const float uo = fexp2(z[3]);   // e^{-zo}
            const float f  = frcp(1.0f + uf);
            const float ig = (1.0f - ug) * frcp((1.0f + ui) * (1.0f + ug));
            c = fmaf(f, c, ig);
            const float w = fexp2(c * M2L2E);                    // e^{-2c}
            const float h = (1.0f - w) * frcp((1.0f + uo) * (1.0f + w)); // o*tanh(c)

            // Broadcast h[0..4] to all 8 lanes of the group (DPP, VALU-rate).
            // Banks within a 16-lane row: 0=lanes0-3,1=4-7,2=8-11,3=12-15.
            const float t04 = dppmov<0x00>(h);        // quad_perm[0,0,0,0]: q0->h0, q1->h4
            h0v = dppupd<0x114, 0xA>(t04, t04);       // row_shr:4 into banks 1,3
            h4v = dppupd<0x104, 0x5>(t04, t04);       // row_shl:4 into banks 0,2
            const float t1 = dppmov<0x55>(h);         // quad_perm[1,1,1,1]
            h1v = dppupd<0x114, 0xA>(t1, t1);
            const float t2 = dppmov<0xAA>(h);         // quad_perm[2,2,2,2]
            h2v = dppupd<0x114, 0xA>(t2, t2);
            const float t3 = dppmov<0xFF>(h);         // quad_perm[3,3,3,3]
            h3v = dppupd<0x114, 0xA>(t3, t3);
        }
        xv = xn;
    }

    // Epilogue: out[b] = relu(h) @ W_fc.T + b_fc, from lane 0 of each group.
    if (lane8 == 0) {
        float acc = b_fc[0];
        acc = fmaf(fmaxf(h0v, 0.0f), W_fc[0], acc);
        acc = fmaf(fmaxf(h1v, 0.0f), W_fc[1], acc);
        acc = fmaf(fmaxf(h2v, 0.0f), W_fc[2], acc);
        acc = fmaf(fmaxf(h3v, 0.0f), W_fc[3], acc);
        acc = fmaf(fmaxf(h4v, 0.0f), W_fc[4], acc);
        out[b] = acc;
    }
}

extern "C" void kernel_launch(void* const* d_in, const int* in_sizes, int n_in,
                              void* d_out, int out_size, void* d_ws, size_t ws_size,
                              hipStream_t stream) {
    const float* x    = (const float*)d_in[0];
    const float* W_ih = (const float*)d_in[1];
    const float* W_hh = (const float*)d_in[2];
    const float* b_ih = (const float*)d_in[3];
    const float* b_hh = (const float*)d_in[4];
    const float* W_fc = (const float*)d_in[5];
    const float* b_fc = (const float*)d_in[6];
    float* out = (float*)d_out;
    const int B = out_size;  // 8192
    const int threads = B * 8;
    lstm_fused8<<<(threads + 255) / 256, 256, 0, stream>>>(
        x, W_ih, W_hh, b_ih, b_hh, W_fc, b_fc, out, B);
}

// Round 3
// 344.580 us; speedup vs baseline: 2.9971x; 1.0867x over previous
//
#include <hip/hip_runtime.h>

// LSTM(H=5, in=1), T=2048, B=8192, + ReLU + FC head.
// Round 3: 8 lanes/element (1024 waves, 1/SIMD) + packed-fp32 math.
// Gate rows paired (i,f) and (g,o) -> v_pk_fma_f32 matvec (half the FMA issue).
// Merged rcp: R = rcp(Ai*Ag*Af); f = Ai*Ag*R; ig = (1-ug)*Af*R  (7 trans/step).
// DPP broadcast of h[0..4] unchanged from Round 2 (verified correct).
// Weights pre-scaled by -log2e (g-rows by -2log2e) so exp2 args are direct.

#define TLEN 2048

typedef float v2f __attribute__((ext_vector_type(2)));

__device__ __forceinline__ float fexp2(float v) { return __builtin_amdgcn_exp2f(v); }
__device__ __forceinline__ float frcp(float v)  { return __builtin_amdgcn_rcpf(v); }
__device__ __forceinline__ v2f fma2(v2f a, v2f b, v2f c) {
    return __builtin_elementwise_fma(a, b, c);
}

template<int CTRL>
__device__ __forceinline__ float dppmov(float v) {
    return __int_as_float(__builtin_amdgcn_mov_dpp(__float_as_int(v), CTRL, 0xF, 0xF, true));
}
template<int CTRL, int BANK_MASK>
__device__ __forceinline__ float dppupd(float old, float v) {
    return __int_as_float(__builtin_amdgcn_update_dpp(
        __float_as_int(old), __float_as_int(v), CTRL, 0xF, BANK_MASK, false));
}

__global__ __launch_bounds__(256, 1) void lstm_fused8p(
    const float* __restrict__ x,      // [B, T, 1]
    const float* __restrict__ W_ih,   // [20, 1]
    const float* __restrict__ W_hh,   // [20, 5]
    const float* __restrict__ b_ih,   // [20]
    const float* __restrict__ b_hh,   // [20]
    const float* __restrict__ W_fc,   // [1, 5]
    const float* __restrict__ b_fc,   // [1]
    float* __restrict__ out, int B)
{
    const int tid = blockIdx.x * 256 + threadIdx.x;
    if (tid >= B * 8) return;
    const int b = tid >> 3;
    const int lane8 = tid & 7;
    const int k = lane8 < 5 ? lane8 : 4;   // owned hidden unit (clamped dup)

    constexpr float L2E = 1.4426950408889634f;
    const float M2L2E = -2.0f * L2E;

    // Packed per-lane weights: .x = row pair's first gate, .y = second.
    // pair01 = (i-row k, f-row 5+k), pair23 = (g-row 10+k, o-row 15+k).
    v2f wih01, wih23, bias01, bias23, whh01[5], whh23[5];
    {
        const int ri = k, rf = 5 + k, rg = 10 + k, ro = 15 + k;
        wih01  = v2f{W_ih[ri] * -L2E,               W_ih[rf] * -L2E};
        wih23  = v2f{W_ih[rg] * M2L2E,              W_ih[ro] * -L2E};
        bias01 = v2f{(b_ih[ri] + b_hh[ri]) * -L2E,  (b_ih[rf] + b_hh[rf]) * -L2E};
        bias23 = v2f{(b_ih[rg] + b_hh[rg]) * M2L2E, (b_ih[ro] + b_hh[ro]) * -L2E};
#pragma unroll
        for (int m = 0; m < 5; ++m) {
            whh01[m] = v2f{W_hh[ri * 5 + m] * -L2E,  W_hh[rf * 5 + m] * -L2E};
            whh23[m] = v2f{W_hh[rg * 5 + m] * M2L2E, W_hh[ro * 5 + m] * -L2E};
        }
    }

    float c = 0.0f;
    float h0v = 0.0f, h1v = 0.0f, h2v = 0.0f, h3v = 0.0f, h4v = 0.0f;

    const float4* xp = reinterpret_cast<const float4*>(x + (size_t)b * TLEN);
    float4 xv = xp[0];
#pragma unroll 1
    for (int t4 = 0; t4 < TLEN / 4; ++t4) {
        const int nxt = (t4 + 1 < TLEN / 4) ? (t4 + 1) : t4;
        float4 xn = xp[nxt];
        float xq[4] = {xv.x, xv.y, xv.z, xv.w};
#pragma unroll
        for (int q = 0; q < 4; ++q) {
            const v2f xt2 = v2f{xq[q], xq[q]};
            const v2f h0s = v2f{h0v, h0v}, h1s = v2f{h1v, h1v}, h2s = v2f{h2v, h2v};
            const v2f h3s = v2f{h3v, h3v}, h4s = v2f{h4v, h4v};

            // z pairs, split-accumulated (shorter dependent chain)
            v2f za01 = fma2(xt2, wih01, bias01);
            za01 = fma2(h0s, whh01[0], za01);
            za01 = fma2(h1s, whh01[1], za01);
            v2f zb01 = fma2(h3s, whh01[3], h2s * whh01[2]);
            zb01 = fma2(h4s, whh01[4], zb01);
            const v2f z01 = za01 + zb01;

            v2f za23 = fma2(xt2, wih23, bias23);
            za23 = fma2(h0s, whh23[0], za23);
            za23 = fma2(h1s, whh23[1], za23);
            v2f zb23 = fma2(h3s, whh23[3], h2s * whh23[2]);
            zb23 = fma2(h4s, whh23[4], zb23);
            const v2f z23 = za23 + zb23;

            const float ui = fexp2(z01.x);   // e^{-zi}
            const float uf = fexp2(z01.y);   // e^{-zf}
            const float ug = fexp2(z23.x);   // e^{-2 zg}
            const float uo = fexp2(z23.y);   // e^{-zo}

            const float Ai = 1.0f + ui, Af = 1.0f + uf;
            const float Ag = 1.0f + ug, Ao = 1.0f + uo;
            const float P  = Ai * Ag;
            const float R  = frcp(P * Af);          // 1/(Ai*Ag*Af)
            const float f  = P * R;                 // sigmoid(zf)
            const float ig = (2.0f - Ag) * (Af * R);// (1-ug)/((1+ui)(1+ug)) = i*g
            c = fmaf(f, c, ig);
            const float wm = fexp2(c * M2L2E);      // e^{-2c}
            const float Aw = 1.0f + wm;
            const float Ro = frcp(Ao * Aw);
            const float h  = (2.0f - Aw) * Ro;      // o * tanh(c)

            // DPP broadcast of h[0..4] to all 8 lanes (unchanged from R2).
            const float t04 = dppmov<0x00>(h);
            h0v = dppupd<0x114, 0xA>(t04, t04);
            h4v = dppupd<0x104, 0x5>(t04, t04);
            const float t1 = dppmov<0x55>(h);
            h1v = dppupd<0x114, 0xA>(t1, t1);
            const float t2 = dppmov<0xAA>(h);
            h2v = dppupd<0x114, 0xA>(t2, t2);
            const float t3 = dppmov<0xFF>(h);
            h3v = dppupd<0x114, 0xA>(t3, t3);
        }
        xv = xn;
    }

    if (lane8 == 0) {
        float acc = b_fc[0];
        acc = fmaf(fmaxf(h0v, 0.0f), W_fc[0], acc);
        acc = fmaf(fmaxf(h1v, 0.0f), W_fc[1], acc);
        acc = fmaf(fmaxf(h2v, 0.0f), W_fc[2], acc);
        acc = fmaf(fmaxf(h3v, 0.0f), W_fc[3], acc);
        acc = fmaf(fmaxf(h4v, 0.0f), W_fc[4], acc);
        out[b] = acc;
    }
}

extern "C" void kernel_launch(void* const* d_in, const int* in_sizes, int n_in,
                              void* d_out, int out_size, void* d_ws, size_t ws_size,
                              hipStream_t stream) {
    const float* x    = (const float*)d_in[0];
    const float* W_ih = (const float*)d_in[1];
    const float* W_hh = (const float*)d_in[2];
    const float* b_ih = (const float*)d_in[3];
    const float* b_hh = (const float*)d_in[4];
    const float* W_fc = (const float*)d_in[5];
    const float* b_fc = (const float*)d_in[6];
    float* out = (float*)d_out;
    const int B = out_size;  // 8192
    const int threads = B * 8;
    lstm_fused8p<<<(threads + 255) / 256, 256, 0, stream>>>(
        x, W_ih, W_hh, b_ih, b_hh, W_fc, b_fc, out, B);
}